// Round 1
// baseline (696.355 us; speedup 1.0000x reference)
//
#include <hip/hip_runtime.h>
#include <math.h>

// WaveLM: logits[b,t,v] = sum_{t'<t} g(id[b,t'], v)
// g(u,v) = 2 * sum_{i,j in 1..H} (A_u/i^dec)(A_v/j^dec) * sinc(2*(f_u*i - f_v*j))
// jnp.sinc(x) = sin(pi x)/(pi x), sinc(0)=1  =>  sinc(2d) = sin(2*pi*d)/(2*pi*d)

constexpr int cB = 4, cT = 512, cV = 8000, cH = 7;

// Kernel A: write C[b,t,v] = g(id[bt], v) directly into out.
// One block per (bt, v-tile of 256). 2048 * 32 = 65536 blocks.
__global__ __launch_bounds__(256) void wavelm_g(
    const int* __restrict__ ids,
    const float* __restrict__ freq,
    const float* __restrict__ amp,
    const float* __restrict__ decay_p,
    float* __restrict__ out)
{
    const int bt = blockIdx.y;                       // 0 .. B*T-1
    const int v  = blockIdx.x * 256 + threadIdx.x;   // 0 .. 8191 (mask v<V)
    const float decay = decay_p[0];

    const int   id  = ids[bt];
    const float f_u = freq[id];
    const float A_u = amp[id];

    float fv = 0.0f, av = 0.0f;
    if (v < cV) { fv = freq[v]; av = amp[v]; }

    // rp[k] = (k+1)^(-decay); exact 1.0 at k=0 (log2(1)=0, exp2(0)=1)
    float rp[cH];
#pragma unroll
    for (int k = 0; k < cH; ++k)
        rp[k] = __powf((float)(k + 1), -decay);

    float fui[cH], aui[cH], fvj[cH], avj[cH];
#pragma unroll
    for (int k = 0; k < cH; ++k) {
        const float hk = (float)(k + 1);
        fui[k] = f_u * hk;  aui[k] = A_u * rp[k];
        fvj[k] = fv  * hk;  avj[k] = av  * rp[k];
    }

    const float TWO_PI = 6.28318530717958647692f;
    float acc = 0.0f;
#pragma unroll
    for (int i = 0; i < cH; ++i) {
        float acci = 0.0f;
#pragma unroll
        for (int j = 0; j < cH; ++j) {
            const float d  = fui[i] - fvj[j];
            // sin(2*pi*d): v_sin_f32 takes revolutions; reduce to [-0.5, 0.5]
            const float r  = d - rintf(d);
            const float sn = __builtin_amdgcn_sinf(r);
            const float q  = sn * __builtin_amdgcn_rcpf(TWO_PI * d);
            const float s  = (d == 0.0f) ? 1.0f : q;   // exact-zero diagonal
            acci = fmaf(avj[j], s, acci);
        }
        acc = fmaf(aui[i], acci, acc);
    }

    if (v < cV)
        out[(size_t)bt * cV + v] = 2.0f * acc;
}

// Kernel B: in-place shifted cumsum over t. One thread per (b, v) chain.
// logits[b,0,v]=0; logits[b,t,v]=sum_{t'<t} C[b,t',v].
__global__ __launch_bounds__(256) void wavelm_scan(float* __restrict__ out)
{
    const int g = blockIdx.x * blockDim.x + threadIdx.x;
    if (g >= cB * cV) return;
    const int b = g / cV;
    const int v = g - b * cV;
    float* p = out + (size_t)b * cT * cV + v;
    float acc = 0.0f;
#pragma unroll 8
    for (int t = 0; t < cT; ++t) {
        const float c = p[(size_t)t * cV];
        p[(size_t)t * cV] = acc;
        acc += c;
    }
}

extern "C" void kernel_launch(void* const* d_in, const int* in_sizes, int n_in,
                              void* d_out, int out_size, void* d_ws, size_t ws_size,
                              hipStream_t stream)
{
    const int*   ids  = (const int*)d_in[0];
    const float* freq = (const float*)d_in[1];
    const float* amp  = (const float*)d_in[2];
    const float* dec  = (const float*)d_in[3];
    // d_in[4] = chunk_size: irrelevant to the math (pure chunking artifact)
    float* out = (float*)d_out;

    dim3 grid((cV + 255) / 256, cB * cT);   // 32 x 2048
    wavelm_g<<<grid, dim3(256), 0, stream>>>(ids, freq, amp, dec, out);

    const int nchains = cB * cV;            // 32000
    wavelm_scan<<<(nchains + 255) / 256, dim3(256), 0, stream>>>(out);
}

// Round 2
// 382.427 us; speedup vs baseline: 1.8209x; 1.8209x over previous
//
#include <hip/hip_runtime.h>
#include <math.h>

// WaveLM: logits[b,t,v] = sum_{t'<t} g(id[b,t'], v)
// g(u,v) = 2 * sum_{i,j in 1..H} (A_u/i^dec)(A_v/j^dec) * sinc(2*(f_u*i - f_v*j))
// sinc(2d) = sin(2*pi*d)/(2*pi*d), sinc(0)=1
//
// R2: transcendental-minimized form.
//  - sin(2*pi*(a_i - b_j)) = sA_i*cB_j - cA_i*sB_j with sin/cos of harmonics
//    built by Chebyshev recurrence from ONE sin+cos per side.
//  - 1/d_ij per i-row (7 values) via Montgomery batch inversion: 1 v_rcp + 19 muls.
//  - (k+1)^-decay via exp2(-decay*log2(k+1)), compile-time log2 constants.
// Per-thread transcendentals: 4 exp2 + 2+2 sin/cos + 7 rcp = 15 (was ~112).

constexpr int cB = 4, cT = 512, cV = 8000, cH = 7;

__global__ __launch_bounds__(256) void wavelm_g(
    const int* __restrict__ ids,
    const float* __restrict__ freq,
    const float* __restrict__ amp,
    const float* __restrict__ decay_p,
    float* __restrict__ out)
{
    const int bt = blockIdx.y;                       // 0 .. B*T-1
    const int v  = blockIdx.x * 256 + threadIdx.x;   // 0 .. 8191
    const float decay = decay_p[0];

    const int   id  = ids[bt];
    const float f_u = freq[id];
    const float A_u = amp[id];

    const int   vc = (v < cV) ? v : 0;
    const float fv = freq[vc];
    const float av = amp[vc];

    // rp[k] = (k+1)^-decay via exp2; log2 constants folded at compile time
    const float p2 = __builtin_amdgcn_exp2f(-decay);                  // 2^-d
    const float p3 = __builtin_amdgcn_exp2f(-decay * 1.5849625007f);  // 3^-d
    const float p5 = __builtin_amdgcn_exp2f(-decay * 2.3219280949f);  // 5^-d
    const float p7 = __builtin_amdgcn_exp2f(-decay * 2.8073549221f);  // 7^-d
    float rp[cH];
    rp[0] = 1.0f; rp[1] = p2; rp[2] = p3; rp[3] = p2 * p2;
    rp[4] = p5;   rp[5] = p2 * p3; rp[6] = p7;

    // u-side: sin/cos of 2*pi*f_u*i via recurrence from base angle
    float sA[cH], cA[cH], aui[cH];
    {
        const float xr = f_u - rintf(f_u);           // revolutions, reduced
        const float s1 = __builtin_amdgcn_sinf(xr);
        const float c1 = __builtin_amdgcn_cosf(xr);
        sA[0] = s1; cA[0] = c1;
#pragma unroll
        for (int i = 1; i < cH; ++i) {
            const float sp = sA[i-1], cp = cA[i-1];
            sA[i] = fmaf(sp, c1,  cp * s1);
            cA[i] = fmaf(cp, c1, -(sp * s1));
        }
#pragma unroll
        for (int i = 0; i < cH; ++i) aui[i] = A_u * rp[i];
    }

    // v-side: b_j = f_v*(j+1); weighted sin/cos; avj for the d==0 diagonal
    const float INV2PI = 0.15915494309189535f;
    float b[cH], sBw[cH], cBw[cH], avj[cH];
    {
        const float xr = fv - rintf(fv);
        const float s1 = __builtin_amdgcn_sinf(xr);
        const float c1 = __builtin_amdgcn_cosf(xr);
        float sB = s1, cB = c1;
#pragma unroll
        for (int j = 0; j < cH; ++j) {
            if (j > 0) {
                const float sp = sB, cp = cB;
                sB = fmaf(sp, c1,  cp * s1);
                cB = fmaf(cp, c1, -(sp * s1));
            }
            b[j]   = fv * (float)(j + 1);
            avj[j] = av * rp[j];
            const float w = avj[j] * INV2PI;
            sBw[j] = sB * w;
            cBw[j] = cB * w;
        }
    }

    float acc = 0.0f;
#pragma unroll
    for (int i = 0; i < cH; ++i) {
        const float ai = f_u * (float)(i + 1);
        float d[cH], dd[cH];
#pragma unroll
        for (int j = 0; j < cH; ++j) {
            d[j]  = ai - b[j];
            dd[j] = (d[j] == 0.0f) ? 1.0f : d[j];
        }
        // Montgomery batch inversion of dd[0..6]
        float p[cH];
        p[0] = dd[0];
#pragma unroll
        for (int j = 1; j < cH; ++j) p[j] = p[j-1] * dd[j];
        float r = __builtin_amdgcn_rcpf(p[cH-1]);
        float inv[cH];
#pragma unroll
        for (int j = cH - 1; j >= 1; --j) {
            inv[j] = r * p[j-1];
            r      = r * dd[j];
        }
        inv[0] = r;

        float acci = 0.0f;
#pragma unroll
        for (int j = 0; j < cH; ++j) {
            // avj[j]/(2pi) * sin(2pi*(a_i-b_j))
            const float sn   = fmaf(sA[i], cBw[j], -(cA[i] * sBw[j]));
            float term = sn * inv[j];
            term = (d[j] == 0.0f) ? avj[j] : term;   // sinc(0)=1 diagonal
            acci += term;
        }
        acc = fmaf(aui[i], acci, acc);
    }

    if (v < cV)
        out[(size_t)bt * cV + v] = 2.0f * acc;
}

// In-place shifted cumsum over t. One thread per (b, v) chain.
__global__ __launch_bounds__(256) void wavelm_scan(float* __restrict__ out)
{
    const int g = blockIdx.x * blockDim.x + threadIdx.x;
    if (g >= cB * cV) return;
    const int b = g / cV;
    const int v = g - b * cV;
    float* p = out + (size_t)b * cT * cV + v;
    float acc = 0.0f;
#pragma unroll 8
    for (int t = 0; t < cT; ++t) {
        const float c = p[(size_t)t * cV];
        p[(size_t)t * cV] = acc;
        acc += c;
    }
}

extern "C" void kernel_launch(void* const* d_in, const int* in_sizes, int n_in,
                              void* d_out, int out_size, void* d_ws, size_t ws_size,
                              hipStream_t stream)
{
    const int*   ids  = (const int*)d_in[0];
    const float* freq = (const float*)d_in[1];
    const float* amp  = (const float*)d_in[2];
    const float* dec  = (const float*)d_in[3];
    float* out = (float*)d_out;

    dim3 grid((cV + 255) / 256, cB * cT);   // 32 x 2048
    wavelm_g<<<grid, dim3(256), 0, stream>>>(ids, freq, amp, dec, out);

    const int nchains = cB * cV;            // 32000
    wavelm_scan<<<(nchains + 255) / 256, dim3(256), 0, stream>>>(out);
}

// Round 3
// 271.798 us; speedup vs baseline: 2.5620x; 1.4070x over previous
//
#include <hip/hip_runtime.h>
#include <math.h>

// WaveLM: logits[b,t,v] = sum_{t'<t} g(id[b,t'], v)
// g(u,v) = 2 * sum_{i,j in 1..H} (A_u/i^dec)(A_v/j^dec) * sinc(2*(f_u*i - f_v*j))
// sinc(2d) = sin(2*pi*d)/(2*pi*d), sinc(0)=1
//
// R3: packed-fp32 form. Each thread computes TWO adjacent v's with
// component-wise code shaped for v_pk_{fma,mul,add}_f32 SLP formation.
// Hot loop is UNGUARDED (no per-pair cndmask): exact-zero / underflow /
// overflow of the batch-inversion products is detected via min/max|p|
// trackers (1-2 v_min/v_max per i-row) and the rare affected lanes
// (v==id, or fp coincidences) redo a fully guarded slow path.
// Scan: kernel A atomically accumulates 64-t-segment column sums into ws;
// scan2 does base + 64-step local scan with 8x the parallelism.

constexpr int cB = 4, cT = 512, cV = 8000, cH = 7;
constexpr int SEG = 8, SEGLEN = 64;          // cT = SEG*SEGLEN

struct pf2 { float x, y; };

__global__ __launch_bounds__(256) void wavelm_g(
    const int* __restrict__ ids,
    const float* __restrict__ freq,
    const float* __restrict__ amp,
    const float* __restrict__ decay_p,
    float* __restrict__ out,
    float* __restrict__ segsum,
    int use_seg)
{
    const int bt = blockIdx.y;                        // 0 .. B*T-1
    const int vh = blockIdx.x * 256 + threadIdx.x;    // pair index
    const int v0 = vh * 2;
    const bool valid = (v0 < cV);
    const int vc = valid ? vh : 0;

    const float decay = decay_p[0];
    const int   id  = ids[bt];
    const float f_u = freq[id];
    const float A_u = amp[id];

    const float2 fv2 = ((const float2*)freq)[vc];
    const float2 av2 = ((const float2*)amp)[vc];

    // rp[k] = (k+1)^-decay via exp2; log2 constants folded at compile time
    const float p2 = __builtin_amdgcn_exp2f(-decay);
    const float p3 = __builtin_amdgcn_exp2f(-decay * 1.5849625007f);
    const float p5 = __builtin_amdgcn_exp2f(-decay * 2.3219280949f);
    const float p7 = __builtin_amdgcn_exp2f(-decay * 2.8073549221f);
    float rp[cH];
    rp[0] = 1.0f; rp[1] = p2; rp[2] = p3; rp[3] = p2 * p2;
    rp[4] = p5;   rp[5] = p2 * p3; rp[6] = p7;

    // ---- u-side (wave-uniform): sin/cos of harmonics via recurrence ----
    float sA[cH], cA[cH], aui[cH];
    {
        const float xr = f_u - rintf(f_u);
        const float s1 = __builtin_amdgcn_sinf(xr);
        const float c1 = __builtin_amdgcn_cosf(xr);
        sA[0] = s1; cA[0] = c1;
#pragma unroll
        for (int i = 1; i < cH; ++i) {
            const float sp = sA[i-1], cp = cA[i-1];
            sA[i] = fmaf(sp, c1,  cp * s1);
            cA[i] = fmaf(cp, c1, -(sp * s1));
        }
#pragma unroll
        for (int i = 0; i < cH; ++i) aui[i] = A_u * rp[i];
    }

    // ---- v-side (packed): b_j, weighted sin/cos ----
    const float INV2PI = 0.15915494309189535f;
    pf2 bang[cH], sBw[cH], cBw[cH];
    {
        pf2 xr;  xr.x = fv2.x - rintf(fv2.x);  xr.y = fv2.y - rintf(fv2.y);
        pf2 s1, c1;
        s1.x = __builtin_amdgcn_sinf(xr.x);  s1.y = __builtin_amdgcn_sinf(xr.y);
        c1.x = __builtin_amdgcn_cosf(xr.x);  c1.y = __builtin_amdgcn_cosf(xr.y);
        pf2 sB = s1, cB = c1;
#pragma unroll
        for (int j = 0; j < cH; ++j) {
            if (j > 0) {
                pf2 sp = sB, cp = cB;
                sB.x = fmaf(sp.x, c1.x,  cp.x * s1.x);
                sB.y = fmaf(sp.y, c1.y,  cp.y * s1.y);
                cB.x = fmaf(cp.x, c1.x, -(sp.x * s1.x));
                cB.y = fmaf(cp.y, c1.y, -(sp.y * s1.y));
            }
            const float hj = (float)(j + 1);
            bang[j].x = fv2.x * hj;  bang[j].y = fv2.y * hj;
            const float wx = av2.x * rp[j] * INV2PI;
            const float wy = av2.y * rp[j] * INV2PI;
            sBw[j].x = sB.x * wx;  sBw[j].y = sB.y * wy;
            cBw[j].x = cB.x * wx;  cBw[j].y = cB.y * wy;
        }
    }

    // ---- hot loop: unguarded batch inversion + angle-addition sin ----
    pf2 acc; acc.x = 0.0f; acc.y = 0.0f;
    float mn = 3.0e38f;      // min |product| tracker (zero/underflow detect)
    float mx = 0.0f;         // max |ptot| tracker (overflow detect)
#pragma unroll
    for (int i = 0; i < cH; ++i) {
        const float ai = f_u * (float)(i + 1);
        pf2 d[cH], p[cH];
#pragma unroll
        for (int j = 0; j < cH; ++j) {
            d[j].x = ai - bang[j].x;
            d[j].y = ai - bang[j].y;
        }
        p[0] = d[0];
#pragma unroll
        for (int j = 1; j < cH; ++j) {
            p[j].x = p[j-1].x * d[j].x;
            p[j].y = p[j-1].y * d[j].y;
        }
        const float ptot = p[cH-1].x * p[cH-1].y;
        mn = fminf(mn, fminf(fabsf(p[cH-1].x), fabsf(p[cH-1].y)));
        mn = fminf(mn, fabsf(ptot));
        mx = fmaxf(mx, fabsf(ptot));
        const float rt = __builtin_amdgcn_rcpf(ptot);
        pf2 r;  r.x = rt * p[cH-1].y;  r.y = rt * p[cH-1].x;   // 1/p6 per comp
        pf2 inv[cH];
#pragma unroll
        for (int j = cH - 1; j >= 1; --j) {
            inv[j].x = r.x * p[j-1].x;
            inv[j].y = r.y * p[j-1].y;
            r.x = r.x * d[j].x;
            r.y = r.y * d[j].y;
        }
        inv[0] = r;

        pf2 acci; acci.x = 0.0f; acci.y = 0.0f;
#pragma unroll
        for (int j = 0; j < cH; ++j) {
            pf2 sn;
            sn.x = fmaf(sA[i], cBw[j].x, -(cA[i] * sBw[j].x));
            sn.y = fmaf(sA[i], cBw[j].y, -(cA[i] * sBw[j].y));
            acci.x = fmaf(sn.x, inv[j].x, acci.x);
            acci.y = fmaf(sn.y, inv[j].y, acci.y);
        }
        acc.x = fmaf(aui[i], acci.x, acc.x);
        acc.y = fmaf(aui[i], acci.y, acc.y);
    }

    // ---- rare slow path: exact-zero d (v==id), underflow, or overflow ----
    if (mn == 0.0f || !(mx <= 3.0e38f)) {
        acc.x = 0.0f; acc.y = 0.0f;
#pragma unroll
        for (int i = 0; i < cH; ++i) {
            float ax = 0.0f, ay = 0.0f;
#pragma unroll
            for (int j = 0; j < cH; ++j) {
                const float avjx = av2.x * rp[j];
                const float avjy = av2.y * rp[j];
                const float dx = f_u * (float)(i + 1) - bang[j].x;
                const float dy = f_u * (float)(i + 1) - bang[j].y;
                const float snx = fmaf(sA[i], cBw[j].x, -(cA[i] * sBw[j].x));
                const float sny = fmaf(sA[i], cBw[j].y, -(cA[i] * sBw[j].y));
                float qx = snx * __builtin_amdgcn_rcpf(dx);
                float qy = sny * __builtin_amdgcn_rcpf(dy);
                qx = (dx == 0.0f) ? avjx : qx;
                qy = (dy == 0.0f) ? avjy : qy;
                ax += qx;  ay += qy;
            }
            acc.x = fmaf(aui[i], ax, acc.x);
            acc.y = fmaf(aui[i], ay, acc.y);
        }
    }

    if (valid) {
        float2 res;  res.x = 2.0f * acc.x;  res.y = 2.0f * acc.y;
        ((float2*)out)[(size_t)bt * (cV/2) + vh] = res;
        if (use_seg) {
            const int b   = bt >> 9;       // / cT
            const int t   = bt & (cT - 1);
            const int seg = t >> 6;        // / SEGLEN
            if (seg < SEG - 1) {           // last segment's sum never needed
                float* w = segsum + ((size_t)(b * SEG + seg)) * cV + v0;
                atomicAdd(w,     res.x);
                atomicAdd(w + 1, res.y);
            }
        }
    }
}

__global__ __launch_bounds__(256) void wavelm_zero(float* __restrict__ p, int n)
{
    const int i = blockIdx.x * 256 + threadIdx.x;
    if (i < n) p[i] = 0.0f;
}

// Segmented scan: blockIdx.y = b*SEG + seg; base = sum of prior segment sums.
__global__ __launch_bounds__(256) void wavelm_scan2(
    float* __restrict__ out, const float* __restrict__ segsum)
{
    const int v = blockIdx.x * 256 + threadIdx.x;
    if (v >= cV) return;
    const int bs  = blockIdx.y;
    const int b   = bs >> 3;
    const int seg = bs & (SEG - 1);
    float base = 0.0f;
    for (int sp = 0; sp < seg; ++sp)
        base += segsum[((size_t)(b * SEG + sp)) * cV + v];
    float* p = out + ((size_t)b * cT + (size_t)seg * SEGLEN) * cV + v;
    float acc = base;
#pragma unroll 8
    for (int k = 0; k < SEGLEN; ++k) {
        const float c = p[(size_t)k * cV];
        p[(size_t)k * cV] = acc;
        acc += c;
    }
}

// Fallback full-chain scan (used if ws is too small for segment sums).
__global__ __launch_bounds__(256) void wavelm_scan(float* __restrict__ out)
{
    const int g = blockIdx.x * blockDim.x + threadIdx.x;
    if (g >= cB * cV) return;
    const int b = g / cV;
    const int v = g - b * cV;
    float* p = out + (size_t)b * cT * cV + v;
    float acc = 0.0f;
#pragma unroll 8
    for (int t = 0; t < cT; ++t) {
        const float c = p[(size_t)t * cV];
        p[(size_t)t * cV] = acc;
        acc += c;
    }
}

extern "C" void kernel_launch(void* const* d_in, const int* in_sizes, int n_in,
                              void* d_out, int out_size, void* d_ws, size_t ws_size,
                              hipStream_t stream)
{
    const int*   ids  = (const int*)d_in[0];
    const float* freq = (const float*)d_in[1];
    const float* amp  = (const float*)d_in[2];
    const float* dec  = (const float*)d_in[3];
    float* out = (float*)d_out;
    float* ws  = (float*)d_ws;

    const int nseg_f = cB * SEG * cV;                 // 256000 floats
    const int use_seg = (ws_size >= (size_t)nseg_f * sizeof(float)) ? 1 : 0;

    if (use_seg) {
        wavelm_zero<<<(nseg_f + 255) / 256, 256, 0, stream>>>(ws, nseg_f);
    }

    dim3 grid((cV / 2 + 255) / 256, cB * cT);         // 16 x 2048
    wavelm_g<<<grid, dim3(256), 0, stream>>>(ids, freq, amp, dec, out, ws, use_seg);

    if (use_seg) {
        dim3 sg((cV + 255) / 256, cB * SEG);          // 32 x 32
        wavelm_scan2<<<sg, dim3(256), 0, stream>>>(out, ws);
    } else {
        const int nchains = cB * cV;
        wavelm_scan<<<(nchains + 255) / 256, dim3(256), 0, stream>>>(out);
    }
}